// Round 8
// baseline (22.223 us; speedup 1.0000x reference)
//
#include <hip/hip_runtime.h>

// YOLO loss (forward only). One thread per cell, but WAVE-DENSE loads:
// each wave owns 64 consecutive cells; lanes load 320 consecutive float4s
// (pred) + 192 consecutive float2s (tgt) -> every global load instruction
// touches 16/8 cache lines instead of 64 (kills L1 tag serialization, the
// ~10us/CU cost that R4 only half-fixed). Redistribution to per-cell layout
// via LDS with WIDE ops only: ds_write_b128/b64 linear (balanced), then
// ds_read_b128 at stride 5*16B (bank group (5l+k)&7 = balanced, 5 odd) and
// ds_read_b64 at stride 3*8B (balanced). No div/mod, no scalar LDS (R3's
// mistake). 26.6KB LDS / 256-thr block. Reduce tail: f64 partials + tiny
// second kernel (proven <1us).

#define SBLK 256
#define WPB  (SBLK / 64)      // 4 waves per block
#define CPW  64               // cells per wave

constexpr float L_COORD = 5.0f;
constexpr float L_NOOBJ = 0.5f;
constexpr float EPS_    = 1e-6f;

__device__ __forceinline__ float clamp01(float x) { return fminf(fmaxf(x, 0.0f), 1.0f); }

__device__ __forceinline__ float iou_f(float l1l, float l1t, float w1, float h1,
                                       float l2l, float l2t, float w2, float h2) {
    float l1r = l1l + w1, l1b = l1t + h1;
    float l2r = l2l + w2, l2b = l2t + h2;
    float a1 = w1 * h1, a2 = w2 * h2;
    bool cont_by2 = (l2l <= l1l) && (l2t <= l1t) && (l2r >= l1r) && (l2b >= l1b);
    bool cont_by1 = (l1l <= l2l) && (l1t <= l2t) && (l1r >= l2r) && (l1b >= l2b);
    bool sep = (l1r <= l2l) || (l2r <= l1l) || (l1b <= l2t) || (l2b <= l1t);
    float iw = fminf(l1r, l2r) - fmaxf(l1l, l2l);
    float ih = fminf(l1b, l2b) - fmaxf(l1t, l2t);
    float inter = iw * ih;
    float gen = inter * __builtin_amdgcn_rcpf(a1 + a2 - inter);
    float r = sep ? 0.0f : gen;
    r = cont_by1 ? a2 * __builtin_amdgcn_rcpf(a1) : r;
    r = cont_by2 ? a1 * __builtin_amdgcn_rcpf(a2) : r;   // outermost where wins
    return r;
}

__global__ __launch_bounds__(SBLK) void yolo_loss_kernel(
        const float* __restrict__ pred, const float* __restrict__ tgt,
        double* __restrict__ partials, int ncells) {
    __shared__ float4 sp[WPB][CPW * 5];   // 4 * 5120 B = 20.0 KB
    __shared__ float2 st[WPB][CPW * 3];   // 4 * 1536 B =  6.0 KB

    const int lane = threadIdx.x & 63;
    const int wid  = threadIdx.x >> 6;
    const int wave_cell0 = (blockIdx.x * WPB + wid) * CPW;
    const int cell = wave_cell0 + lane;

    // ---- wave-dense global loads (clamped for a possible tail wave) ----
    const float4* p4g = reinterpret_cast<const float4*>(pred);
    const float2* t2g = reinterpret_cast<const float2*>(tgt);
    const int maxp4 = ncells * 5 - 1;
    const int maxt2 = ncells * 3 - 1;
    const int pbase = wave_cell0 * 5;
    const int tbase = wave_cell0 * 3;

    float4 pr[5];
    #pragma unroll
    for (int k = 0; k < 5; ++k)
        pr[k] = p4g[min(pbase + k * CPW + lane, maxp4)];
    float2 tr[3];
    #pragma unroll
    for (int k = 0; k < 3; ++k)
        tr[k] = t2g[min(tbase + k * CPW + lane, maxt2)];

    // ---- LDS redistribution: wide writes (linear) ----
    #pragma unroll
    for (int k = 0; k < 5; ++k)
        sp[wid][k * CPW + lane] = pr[k];
    #pragma unroll
    for (int k = 0; k < 3; ++k)
        st[wid][k * CPW + lane] = tr[k];
    __syncthreads();

    // ---- per-cell wide reads (bank-balanced: strides 5 and 3 are odd) ----
    float4 pa = sp[wid][lane * 5 + 0];
    float4 pb = sp[wid][lane * 5 + 1];
    float4 pc = sp[wid][lane * 5 + 2];
    float4 pd = sp[wid][lane * 5 + 3];
    float4 pe = sp[wid][lane * 5 + 4];
    float2 t0 = st[wid][lane * 3 + 0];
    float2 t1 = st[wid][lane * 3 + 1];
    float2 tc = st[wid][lane * 3 + 2];

    float total = 0.0f;
    {
        float conf = tc.x;
        float coo = (conf > 0.0f) ? 1.0f : 0.0f;
        float noo = (conf == 0.0f) ? 1.0f : 0.0f;

        float d0 = pb.x - conf, d1 = pc.y - conf;
        float noobj = noo * (d0 * d0 + d1 * d1);

        float b0l = pa.x, b0t = pa.y, b0w = pa.z, b0h = pa.w, b0c = pb.x;
        float b1l = pb.y, b1t = pb.z, b1w = pb.w, b1h = pc.x, b1c = pc.y;
        float btl = t0.x, btt = t0.y, btw = t1.x, bth = t1.y;

        float iou0 = iou_f(b0l, b0t, b0w, b0h, btl, btt, btw, bth);
        float iou1 = iou_f(b1l, b1t, b1w, b1h, btl, btt, btw, bth);
        bool pick0 = (iou0 >= iou1);
        float max_iou = pick0 ? iou0 : iou1;

        float rl = pick0 ? b0l : b1l;
        float rt = pick0 ? b0t : b1t;
        float rw = pick0 ? b0w : b1w;
        float rh = pick0 ? b0h : b1h;
        float rc = pick0 ? b0c : b1c;
        float nc = pick0 ? b1c : b0c;

        float cd = rc - max_iou;
        float contain = cd * cd;
        float not_contain = nc * nc;

        float ex = clamp01(rl) - clamp01(btl);
        float ey = clamp01(rt) - clamp01(btt);
        float sw = __builtin_amdgcn_sqrtf(fminf(fmaxf(rw, EPS_), 1.0f))
                 - __builtin_amdgcn_sqrtf(fminf(fmaxf(btw, EPS_), 1.0f));
        float sh = __builtin_amdgcn_sqrtf(fminf(fmaxf(rh, EPS_), 1.0f))
                 - __builtin_amdgcn_sqrtf(fminf(fmaxf(bth, EPS_), 1.0f));
        float loc = ex * ex + ey * ey + sw * sw + sh * sh;

        float lg0 = pc.z, lg1 = pc.w;
        float lg2 = pd.x, lg3 = pd.y, lg4 = pd.z, lg5 = pd.w;
        float lg6 = pe.x, lg7 = pe.y, lg8 = pe.z, lg9 = pe.w;
        float m = fmaxf(lg0, lg1);
        m = fmaxf(m, fmaxf(lg2, lg3));
        m = fmaxf(m, fmaxf(lg4, lg5));
        m = fmaxf(m, fmaxf(lg6, lg7));
        m = fmaxf(m, fmaxf(lg8, lg9));
        float ssum = __expf(lg0 - m) + __expf(lg1 - m) + __expf(lg2 - m) +
                     __expf(lg3 - m) + __expf(lg4 - m) + __expf(lg5 - m) +
                     __expf(lg6 - m) + __expf(lg7 - m) + __expf(lg8 - m) +
                     __expf(lg9 - m);
        float logz = m + __logf(ssum);
        int ci = (int)tc.y;
        float picked = lg0;
        picked = (ci == 1) ? lg1 : picked;
        picked = (ci == 2) ? lg2 : picked;
        picked = (ci == 3) ? lg3 : picked;
        picked = (ci == 4) ? lg4 : picked;
        picked = (ci == 5) ? lg5 : picked;
        picked = (ci == 6) ? lg6 : picked;
        picked = (ci == 7) ? lg7 : picked;
        picked = (ci == 8) ? lg8 : picked;
        picked = (ci == 9) ? lg9 : picked;
        float cls_loss = logz - picked;

        total = L_COORD * (coo * loc)
              + 2.0f * (coo * contain)
              + (coo * not_contain)
              + L_NOOBJ * noobj
              + coo * cls_loss;
        total = (cell < ncells) ? total : 0.0f;   // tail lanes contribute 0
    }

    // block reduce: f32 wave shuffle -> LDS -> one f64 store per block
    float v = total;
    #pragma unroll
    for (int off = 32; off > 0; off >>= 1)
        v += __shfl_down(v, off, 64);
    __shared__ float smw[WPB];
    if (lane == 0) smw[wid] = v;
    __syncthreads();
    if (threadIdx.x == 0) {
        double s = 0.0;
        #pragma unroll
        for (int w = 0; w < WPB; ++w) s += (double)smw[w];
        partials[blockIdx.x] = s;   // no atomic: unique slot per block
    }
}

#define RBLK 1024

__global__ __launch_bounds__(RBLK) void yolo_reduce_kernel(
        const double* __restrict__ partials, int nparts,
        float* __restrict__ out, double invN) {
    double v = 0.0;
    for (int idx = threadIdx.x; idx < nparts; idx += RBLK)
        v += partials[idx];
    #pragma unroll
    for (int off = 32; off > 0; off >>= 1)
        v += __shfl_down(v, off, 64);
    __shared__ double sm[RBLK / 64];
    int lane = threadIdx.x & 63;
    int wid  = threadIdx.x >> 6;
    if (lane == 0) sm[wid] = v;
    __syncthreads();
    if (threadIdx.x == 0) {
        double s = 0.0;
        #pragma unroll
        for (int w = 0; w < RBLK / 64; ++w) s += sm[w];
        out[0] = (float)(s * invN);
    }
}

extern "C" void kernel_launch(void* const* d_in, const int* in_sizes, int n_in,
                              void* d_out, int out_size, void* d_ws, size_t ws_size,
                              hipStream_t stream) {
    const float* pred = (const float*)d_in[0];
    const float* tgt  = (const float*)d_in[1];
    int ncells = in_sizes[0] / 20;          // N*7*7 = 802816
    int N = ncells / 49;

    int nblocks = (ncells + SBLK - 1) / SBLK;   // 3136 for the bench shape
    yolo_loss_kernel<<<nblocks, SBLK, 0, stream>>>(pred, tgt, (double*)d_ws, ncells);
    yolo_reduce_kernel<<<1, RBLK, 0, stream>>>((const double*)d_ws, nblocks,
                                               (float*)d_out, 1.0 / (double)N);
}